// Round 2
// baseline (849.446 us; speedup 1.0000x reference)
//
#include <hip/hip_runtime.h>
#include <stdint.h>

#define B_     32
#define S_     1024
#define D_     1280
#define CROSS_ 768
#define NTOK   16
#define SCALE_ 0.125f

typedef __bf16 bf16x8 __attribute__((ext_vector_type(8)));
typedef float  f32x4  __attribute__((ext_vector_type(4)));
typedef unsigned short ushort_t;
typedef unsigned int   uint_t;

__device__ __forceinline__ float b2f(ushort_t h){ return __uint_as_float(((uint_t)h)<<16); }
__device__ __forceinline__ ushort_t f2b(float f){
  uint_t u = __float_as_uint(f);
  u += 0x7FFFu + ((u>>16)&1u);           // RNE
  return (ushort_t)(u>>16);
}
__device__ __forceinline__ uint_t pk2(float x, float y){
  return (uint_t)f2b(x) | ((uint_t)f2b(y)<<16);
}

__device__ __forceinline__ void gload_lds16(const void* g, void* l){
  __builtin_amdgcn_global_load_lds((const __attribute__((address_space(1))) void*)g,
                                   (__attribute__((address_space(3))) void*)l, 16, 0, 0);
}

// ------------------------------------------------------------ cvt f32->bf16
struct CvtArgs { const float* src[7]; ushort_t* dst[7]; int n[7]; };
__global__ void cvt_kernel(CvtArgs a){
  int t = blockIdx.y;
  const float* s = a.src[t]; ushort_t* d = a.dst[t]; int n = a.n[t];
  int i = (blockIdx.x*blockDim.x + threadIdx.x)*4;
  if(i >= n) return;
  float4 v = *(const float4*)(s+i);
  uint2 o; o.x = pk2(v.x,v.y); o.y = pk2(v.z,v.w);
  *(uint2*)(d+i) = o;
}

// ---------------------------------------------------------------- gates ----
__global__ void gates_kernel(const float* __restrict__ enc,
                             const float* __restrict__ w_gate,
                             const float* __restrict__ b_gate,
                             const float* __restrict__ aLog,
                             const float* __restrict__ dLog,
                             float* __restrict__ gates){
  int b = blockIdx.x, tid = threadIdx.x;
  __shared__ float red[256];
  float acc = 0.f;
  for(int k = tid; k < CROSS_; k += 256){
    float s = 0.f;
    for(int t = 0; t < NTOK; ++t)
      s += enc[(size_t)(b*48 + t)*CROSS_ + k];       // dis tokens = enc[:, :16]
    acc += w_gate[k] * s;
  }
  red[tid] = acc; __syncthreads();
  for(int off = 128; off > 0; off >>= 1){
    if(tid < off) red[tid] += red[tid+off];
    __syncthreads();
  }
  if(tid == 0){
    float shift = red[0]*(1.f/16.f) + b_gate[0];
    gates[b*2+0] = 1.f/(1.f+__expf(shift - aLog[0]));     // sigmoid(aLog - shift)
    gates[b*2+1] = 1.f/(1.f+__expf(-(dLog[0] + shift)));  // sigmoid(dLog + shift)
  }
}

// --------------------------------------------------------------- kv gemm ---
// C[tau][b][t][n] = tokens(tau) @ W(tau)^T ; M=512 (b*16+t), N=1280, K=768
__global__ __launch_bounds__(256) void kv_gemm(const ushort_t* __restrict__ enc,
      const ushort_t* __restrict__ wk,  const ushort_t* __restrict__ wv,
      const ushort_t* __restrict__ wkd, const ushort_t* __restrict__ wvd,
      ushort_t* __restrict__ kv){
  __shared__ __align__(16) ushort_t As[128*64];
  __shared__ __align__(16) ushort_t Bs[128*64];
  const int tau = blockIdx.z;
  const ushort_t* W = (tau==0)? wk : (tau==1)? wv : (tau==2)? wkd : wvd;
  const int tok_off = (tau < 2) ? NTOK : 0;   // anat = enc[:,16:32], dis = enc[:,0:16]
  const int m0 = blockIdx.x*128, n0 = blockIdx.y*128;
  const int tid = threadIdx.x, l = tid & 63, w = tid >> 6;
  const int wm = (w&1)*64, wn = (w>>1)*64;
  const f32x4 fz = {0.f,0.f,0.f,0.f};
  f32x4 acc[4][4];
  #pragma unroll
  for(int i=0;i<4;++i){
    #pragma unroll
    for(int j=0;j<4;++j) acc[i][j] = fz;
  }
  for(int kt = 0; kt < CROSS_/64; ++kt){
    const int k0 = kt*64;
    #pragma unroll
    for(int i=0;i<4;++i){
      int row = (w*4+i)*8 + (l>>3);
      int c   = l & 7;
      int gm  = m0 + row;
      int er  = (gm>>4)*48 + tok_off + (gm&15);
      gload_lds16(enc + (size_t)er*CROSS_ + k0 + c*8, As + (w*4+i)*512);
      gload_lds16(W  + (size_t)(n0+row)*CROSS_ + k0 + c*8, Bs + (w*4+i)*512);
    }
    __syncthreads();
    #pragma unroll
    for(int ks = 0; ks < 64; ks += 32){
      bf16x8 a[4], bq[4];
      #pragma unroll
      for(int i=0;i<4;++i) a[i]  = *(const bf16x8*)&As[(wm+i*16+(l&15))*64 + ks + (l>>4)*8];
      #pragma unroll
      for(int j=0;j<4;++j) bq[j] = *(const bf16x8*)&Bs[(wn+j*16+(l&15))*64 + ks + (l>>4)*8];
      #pragma unroll
      for(int i=0;i<4;++i){
        #pragma unroll
        for(int j=0;j<4;++j)
          acc[i][j] = __builtin_amdgcn_mfma_f32_16x16x32_bf16(a[i], bq[j], acc[i][j], 0,0,0);
      }
    }
    __syncthreads();
  }
  #pragma unroll
  for(int i=0;i<4;++i){
    #pragma unroll
    for(int j=0;j<4;++j){
      #pragma unroll
      for(int r=0;r<4;++r){
        int m = m0 + wm + i*16 + (l>>4)*4 + r;
        int n = n0 + wn + j*16 + (l&15);
        int b = m >> 4, t = m & 15;
        kv[(((size_t)tau*B_ + b)*NTOK + t)*D_ + n] = f2b(acc[i][j][r]);
      }
    }
  }
}

// ------------------------------------------------- gemm1 + fused attention -
// q = X @ Wq^T for a 128x128 tile (= 128 s-rows x 2 heads), then attention
// against 16 anat + 16 dis keys, gated mix, z written bf16 to Z.
__global__ __launch_bounds__(256,2) void gemm1_attn(
      const float* __restrict__ X, const ushort_t* __restrict__ Wq,
      const ushort_t* __restrict__ kv, const float* __restrict__ gates,
      ushort_t* __restrict__ Z){
  __shared__ __align__(16) union {
    struct { ushort_t As[128*64]; ushort_t Bs[128*64]; } st;              // 32 KB
    struct { union { ushort_t qs[128*136];                                // 34816 B
                     ushort_t ps[4][64*40]; } u;                          // 20480 B
             ushort_t ks[2*2*16*72];                                      //  9216 B
             ushort_t vts[2*64*40]; } ep;                                 // 10240 B
  } sm;                                                                   // 54272 B
  const int m0 = blockIdx.x*128, n0 = blockIdx.y*128;
  const int tid = threadIdx.x, l = tid & 63, w = tid >> 6;
  const int wm = (w&1)*64, wn = (w>>1)*64;
  const int b = m0 >> 10;                       // 1024 rows per batch
  const f32x4 fz = {0.f,0.f,0.f,0.f};
  f32x4 acc[4][4];
  #pragma unroll
  for(int i=0;i<4;++i){
    #pragma unroll
    for(int j=0;j<4;++j) acc[i][j] = fz;
  }
  const int ar = tid>>1, ah = (tid&1)*32;       // A-staging: thread -> (row, 32-col half)
  for(int kt = 0; kt < D_/64; ++kt){
    const int k0 = kt*64;
    // B: async bf16 global->LDS
    #pragma unroll
    for(int i=0;i<4;++i){
      int row = (w*4+i)*8 + (l>>3);
      int c   = l & 7;
      gload_lds16(Wq + (size_t)(n0+row)*D_ + k0 + c*8, sm.st.Bs + (w*4+i)*512);
    }
    // A: f32 load + cvt -> bf16 LDS
    {
      const float* xp = X + (size_t)(m0+ar)*D_ + k0 + ah;
      float4 v0 = *(const float4*)(xp+ 0), v1 = *(const float4*)(xp+ 4);
      float4 v2 = *(const float4*)(xp+ 8), v3 = *(const float4*)(xp+12);
      float4 v4 = *(const float4*)(xp+16), v5 = *(const float4*)(xp+20);
      float4 v6 = *(const float4*)(xp+24), v7 = *(const float4*)(xp+28);
      uint4 o0 = { pk2(v0.x,v0.y), pk2(v0.z,v0.w), pk2(v1.x,v1.y), pk2(v1.z,v1.w) };
      uint4 o1 = { pk2(v2.x,v2.y), pk2(v2.z,v2.w), pk2(v3.x,v3.y), pk2(v3.z,v3.w) };
      uint4 o2 = { pk2(v4.x,v4.y), pk2(v4.z,v4.w), pk2(v5.x,v5.y), pk2(v5.z,v5.w) };
      uint4 o3 = { pk2(v6.x,v6.y), pk2(v6.z,v6.w), pk2(v7.x,v7.y), pk2(v7.z,v7.w) };
      *(uint4*)&sm.st.As[ar*64 + ah +  0] = o0;
      *(uint4*)&sm.st.As[ar*64 + ah +  8] = o1;
      *(uint4*)&sm.st.As[ar*64 + ah + 16] = o2;
      *(uint4*)&sm.st.As[ar*64 + ah + 24] = o3;
    }
    __syncthreads();
    #pragma unroll
    for(int ks = 0; ks < 64; ks += 32){
      bf16x8 a[4], bq[4];
      #pragma unroll
      for(int i=0;i<4;++i) a[i]  = *(const bf16x8*)&sm.st.As[(wm+i*16+(l&15))*64 + ks + (l>>4)*8];
      #pragma unroll
      for(int j=0;j<4;++j) bq[j] = *(const bf16x8*)&sm.st.Bs[(wn+j*16+(l&15))*64 + ks + (l>>4)*8];
      #pragma unroll
      for(int i=0;i<4;++i){
        #pragma unroll
        for(int j=0;j<4;++j)
          acc[i][j] = __builtin_amdgcn_mfma_f32_16x16x32_bf16(a[i], bq[j], acc[i][j], 0,0,0);
      }
    }
    __syncthreads();
  }
  // --- epilogue: q tile -> LDS (bf16), stage K (row-major) and V^T ---------
  #pragma unroll
  for(int i=0;i<4;++i){
    #pragma unroll
    for(int j=0;j<4;++j){
      #pragma unroll
      for(int r=0;r<4;++r)
        sm.ep.u.qs[(wm+i*16+(l>>4)*4+r)*136 + wn + j*16 + (l&15)] = f2b(acc[i][j][r]);
    }
  }
  // K: ks[h][tk][t][d]  (tk: 0=k_anat(tensor0), 1=k_dis(tensor2))
  for(int id = tid; id < 512; id += 256){
    int h  = id >> 8, rem = id & 255;
    int tk = rem >> 7, t = (rem>>3)&15, c = rem&7;
    int tensor = tk*2;
    const ushort_t* src = kv + (((size_t)tensor*B_ + b)*NTOK + t)*D_ + n0 + h*64 + c*8;
    *(uint4*)&sm.ep.ks[((h*2+tk)*16 + t)*72 + c*8] = *(const uint4*)src;
  }
  // V^T: vts[h][d][t'] with t' = t + 16*(dis)  (tensor 1 = v_anat, 3 = v_dis)
  for(int id = tid; id < 512; id += 256){
    int h = id >> 8, rem = id & 255;
    int tp = rem >> 3, c = rem & 7;
    int tensor = (tp < 16) ? 1 : 3;
    int t = tp & 15;
    const ushort_t* src = kv + (((size_t)tensor*B_ + b)*NTOK + t)*D_ + n0 + h*64 + c*8;
    uint4 v = *(const uint4*)src;
    const ushort_t* pv = (const ushort_t*)&v;
    #pragma unroll
    for(int e=0;e<8;++e) sm.ep.vts[(h*64 + c*8 + e)*40 + tp] = pv[e];
  }
  __syncthreads();
  // --- scores: QK^T via MFMA (wave = one head h, 64 s-rows) ---------------
  const int h = w >> 1, ws0 = (w&1)*64;
  const float gA = gates[b*2+0], gD = gates[b*2+1];
  f32x4 scA[4], scD[4];
  #pragma unroll
  for(int i=0;i<4;++i){ scA[i] = fz; scD[i] = fz; }
  #pragma unroll
  for(int ks0 = 0; ks0 < 64; ks0 += 32){
    bf16x8 qf[4];
    #pragma unroll
    for(int i=0;i<4;++i)
      qf[i] = *(const bf16x8*)&sm.ep.u.qs[(ws0+i*16+(l&15))*136 + h*64 + ks0 + (l>>4)*8];
    bf16x8 kA = *(const bf16x8*)&sm.ep.ks[((h*2+0)*16 + (l&15))*72 + ks0 + (l>>4)*8];
    bf16x8 kD = *(const bf16x8*)&sm.ep.ks[((h*2+1)*16 + (l&15))*72 + ks0 + (l>>4)*8];
    #pragma unroll
    for(int i=0;i<4;++i){
      scA[i] = __builtin_amdgcn_mfma_f32_16x16x32_bf16(qf[i], kA, scA[i], 0,0,0);
      scD[i] = __builtin_amdgcn_mfma_f32_16x16x32_bf16(qf[i], kD, scD[i], 0,0,0);
    }
  }
  __syncthreads();   // qs region dead; reuse for per-wave ps
  // --- softmax over 16 keys (t = lane&15), separate per tensor, gated -----
  #pragma unroll
  for(int i=0;i<4;++i){
    #pragma unroll
    for(int r=0;r<4;++r){
      float vA = scA[i][r]*SCALE_, vD = scD[i][r]*SCALE_;
      float mA = vA, mD = vD;
      #pragma unroll
      for(int off=1; off<16; off<<=1){
        mA = fmaxf(mA, __shfl_xor(mA, off));
        mD = fmaxf(mD, __shfl_xor(mD, off));
      }
      float eA = __expf(vA - mA), eD = __expf(vD - mD);
      float sA = eA, sD = eD;
      #pragma unroll
      for(int off=1; off<16; off<<=1){
        sA += __shfl_xor(sA, off);
        sD += __shfl_xor(sD, off);
      }
      int lr = i*16 + (l>>4)*4 + r;           // local row within wave's strip
      sm.ep.u.ps[w][lr*40 + 0  + (l&15)] = f2b(gA*eA/sA);
      sm.ep.u.ps[w][lr*40 + 16 + (l&15)] = f2b(gD*eD/sD);
    }
  }
  // --- PV: [gA*P_A | gD*P_D] (64x32) @ [V_A;V_D] (32x64), K=32 one MFMA ---
  f32x4 z[4][4];
  #pragma unroll
  for(int i=0;i<4;++i){
    #pragma unroll
    for(int j=0;j<4;++j) z[i][j] = fz;
  }
  bf16x8 pa[4], vb[4];
  #pragma unroll
  for(int i=0;i<4;++i) pa[i] = *(const bf16x8*)&sm.ep.u.ps[w][(i*16+(l&15))*40 + (l>>4)*8];
  #pragma unroll
  for(int j=0;j<4;++j) vb[j] = *(const bf16x8*)&sm.ep.vts[(h*64 + j*16 + (l&15))*40 + (l>>4)*8];
  #pragma unroll
  for(int i=0;i<4;++i){
    #pragma unroll
    for(int j=0;j<4;++j)
      z[i][j] = __builtin_amdgcn_mfma_f32_16x16x32_bf16(pa[i], vb[j], z[i][j], 0,0,0);
  }
  #pragma unroll
  for(int i=0;i<4;++i){
    #pragma unroll
    for(int j=0;j<4;++j){
      #pragma unroll
      for(int r=0;r<4;++r){
        int row = m0 + ws0 + i*16 + (l>>4)*4 + r;
        int col = n0 + h*64 + j*16 + (l&15);
        Z[(size_t)row*D_ + col] = f2b(z[i][j][r]);
      }
    }
  }
}

// ----------------------------------------------- gemm2: out-proj + resid ---
__global__ __launch_bounds__(256) void gemm2(
      const ushort_t* __restrict__ Zin, const ushort_t* __restrict__ Wo,
      const float* __restrict__ bias, const float* __restrict__ resid,
      float* __restrict__ out){
  __shared__ __align__(16) ushort_t As[128*64];
  __shared__ __align__(16) ushort_t Bs[128*64];
  const int m0 = blockIdx.x*128, n0 = blockIdx.y*128;
  const int tid = threadIdx.x, l = tid & 63, w = tid >> 6;
  const int wm = (w&1)*64, wn = (w>>1)*64;
  const f32x4 fz = {0.f,0.f,0.f,0.f};
  f32x4 acc[4][4];
  #pragma unroll
  for(int i=0;i<4;++i){
    #pragma unroll
    for(int j=0;j<4;++j) acc[i][j] = fz;
  }
  for(int kt = 0; kt < D_/64; ++kt){
    const int k0 = kt*64;
    #pragma unroll
    for(int i=0;i<4;++i){
      int row = (w*4+i)*8 + (l>>3);
      int c   = l & 7;
      gload_lds16(Zin + (size_t)(m0+row)*D_ + k0 + c*8, As + (w*4+i)*512);
      gload_lds16(Wo  + (size_t)(n0+row)*D_ + k0 + c*8, Bs + (w*4+i)*512);
    }
    __syncthreads();
    #pragma unroll
    for(int ks = 0; ks < 64; ks += 32){
      bf16x8 a[4], bq[4];
      #pragma unroll
      for(int i=0;i<4;++i) a[i]  = *(const bf16x8*)&As[(wm+i*16+(l&15))*64 + ks + (l>>4)*8];
      #pragma unroll
      for(int j=0;j<4;++j) bq[j] = *(const bf16x8*)&Bs[(wn+j*16+(l&15))*64 + ks + (l>>4)*8];
      #pragma unroll
      for(int i=0;i<4;++i){
        #pragma unroll
        for(int j=0;j<4;++j)
          acc[i][j] = __builtin_amdgcn_mfma_f32_16x16x32_bf16(a[i], bq[j], acc[i][j], 0,0,0);
      }
    }
    __syncthreads();
  }
  float bj[4];
  #pragma unroll
  for(int j=0;j<4;++j) bj[j] = bias[n0 + wn + j*16 + (l&15)];
  #pragma unroll
  for(int i=0;i<4;++i){
    #pragma unroll
    for(int j=0;j<4;++j){
      #pragma unroll
      for(int r=0;r<4;++r){
        int m = m0 + wm + i*16 + (l>>4)*4 + r;
        int n = n0 + wn + j*16 + (l&15);
        out[(size_t)m*D_ + n] = acc[i][j][r] + bj[j] + resid[(size_t)m*D_ + n];
      }
    }
  }
}

// --------------------------------------------------------------------------
extern "C" void kernel_launch(void* const* d_in, const int* in_sizes, int n_in,
                              void* d_out, int out_size, void* d_ws, size_t ws_size,
                              hipStream_t stream){
  const float* hidden = (const float*)d_in[0];
  const float* enc    = (const float*)d_in[1];
  const float* w_q    = (const float*)d_in[2];
  const float* w_k    = (const float*)d_in[3];
  const float* w_v    = (const float*)d_in[4];
  const float* w_kd   = (const float*)d_in[5];
  const float* w_vd   = (const float*)d_in[6];
  const float* w_gate = (const float*)d_in[7];
  const float* b_gate = (const float*)d_in[8];
  const float* aLog   = (const float*)d_in[9];
  const float* dLog   = (const float*)d_in[10];
  const float* w_out  = (const float*)d_in[11];
  const float* b_out  = (const float*)d_in[12];
  float* out = (float*)d_out;

  char* ws = (char*)d_ws;
  ushort_t* z_bf   = (ushort_t*)(ws + 0);           // 83,886,080 B
  ushort_t* kv_bf  = (ushort_t*)(ws + 83886080);    //  5,242,880 B
  ushort_t* wq_bf  = (ushort_t*)(ws + 89128960);    //  3,276,800 B
  ushort_t* wk_bf  = (ushort_t*)(ws + 92405760);    //  1,966,080 B
  ushort_t* wv_bf  = (ushort_t*)(ws + 94371840);    //  1,966,080 B
  ushort_t* wkd_bf = (ushort_t*)(ws + 96337920);    //  1,966,080 B
  ushort_t* wvd_bf = (ushort_t*)(ws + 98304000);    //  1,966,080 B
  ushort_t* wo_bf  = (ushort_t*)(ws + 100270080);   //  3,276,800 B
  ushort_t* enc_bf = (ushort_t*)(ws + 103546880);   //  2,359,296 B
  float*    gates  = (float*)   (ws + 105906176);   //        256 B

  CvtArgs ca;
  ca.src[0]=w_q;   ca.dst[0]=wq_bf;  ca.n[0]=D_*D_;
  ca.src[1]=w_k;   ca.dst[1]=wk_bf;  ca.n[1]=D_*CROSS_;
  ca.src[2]=w_v;   ca.dst[2]=wv_bf;  ca.n[2]=D_*CROSS_;
  ca.src[3]=w_kd;  ca.dst[3]=wkd_bf; ca.n[3]=D_*CROSS_;
  ca.src[4]=w_vd;  ca.dst[4]=wvd_bf; ca.n[4]=D_*CROSS_;
  ca.src[5]=w_out; ca.dst[5]=wo_bf;  ca.n[5]=D_*D_;
  ca.src[6]=enc;   ca.dst[6]=enc_bf; ca.n[6]=B_*48*CROSS_;
  cvt_kernel<<<dim3(1600,7), 256, 0, stream>>>(ca);

  gates_kernel<<<32, 256, 0, stream>>>(enc, w_gate, b_gate, aLog, dLog, gates);
  kv_gemm<<<dim3(4,10,4), 256, 0, stream>>>(enc_bf, wk_bf, wv_bf, wkd_bf, wvd_bf, kv_bf);
  gemm1_attn<<<dim3(256,10), 256, 0, stream>>>(hidden, wq_bf, kv_bf, gates, z_bf);
  gemm2<<<dim3(256,10), 256, 0, stream>>>(z_bf, wo_bf, b_out, hidden, out);
}

// Round 3
// 735.791 us; speedup vs baseline: 1.1545x; 1.1545x over previous
//
#include <hip/hip_runtime.h>
#include <stdint.h>

#define B_     32
#define S_     1024
#define D_     1280
#define CROSS_ 768
#define NTOK   16
#define SCALE_ 0.125f

typedef __bf16 bf16x8 __attribute__((ext_vector_type(8)));
typedef float  f32x4  __attribute__((ext_vector_type(4)));
typedef unsigned short ushort_t;
typedef unsigned int   uint_t;

__device__ __forceinline__ float b2f(ushort_t h){ return __uint_as_float(((uint_t)h)<<16); }
__device__ __forceinline__ ushort_t f2b(float f){
  uint_t u = __float_as_uint(f);
  u += 0x7FFFu + ((u>>16)&1u);           // RNE
  return (ushort_t)(u>>16);
}
__device__ __forceinline__ uint_t pk2(float x, float y){
  return (uint_t)f2b(x) | ((uint_t)f2b(y)<<16);
}

__device__ __forceinline__ void gload_lds16(const void* g, void* l){
  __builtin_amdgcn_global_load_lds((const __attribute__((address_space(1))) void*)g,
                                   (__attribute__((address_space(3))) void*)l, 16, 0, 0);
}

// XCD-grouping swizzle: all 10 n-tiles of one m-strip land on the same XCD
// consecutively (block i -> XCD i%8 heuristic), so the A-strip stays in L2.
__device__ __forceinline__ void decode_tile(int lin, int& m0, int& n0){
  int xcd = lin & 7, slot = lin >> 3;
  int m_tile = xcd + 8*(slot/10);
  int n_tile = slot - (slot/10)*10;
  m0 = m_tile*128; n0 = n_tile*128;
}

// ------------------------------------------------------------ cvt f32->bf16
struct CvtArgs { const float* src[7]; ushort_t* dst[7]; int n[7]; };
__global__ void cvt_kernel(CvtArgs a){
  int t = blockIdx.y;
  const float* s = a.src[t]; ushort_t* d = a.dst[t]; int n = a.n[t];
  int i = (blockIdx.x*blockDim.x + threadIdx.x)*4;
  if(i >= n) return;
  float4 v = *(const float4*)(s+i);
  uint2 o; o.x = pk2(v.x,v.y); o.y = pk2(v.z,v.w);
  *(uint2*)(d+i) = o;
}

__global__ void cvt_big(const float* __restrict__ s, ushort_t* __restrict__ d, int n){
  int i = (blockIdx.x*blockDim.x + threadIdx.x)*8;
  if(i >= n) return;
  float4 v0 = *(const float4*)(s+i), v1 = *(const float4*)(s+i+4);
  uint4 o = { pk2(v0.x,v0.y), pk2(v0.z,v0.w), pk2(v1.x,v1.y), pk2(v1.z,v1.w) };
  *(uint4*)(d+i) = o;
}

// ---------------------------------------------------------------- gates ----
__global__ void gates_kernel(const float* __restrict__ enc,
                             const float* __restrict__ w_gate,
                             const float* __restrict__ b_gate,
                             const float* __restrict__ aLog,
                             const float* __restrict__ dLog,
                             float* __restrict__ gates){
  int b = blockIdx.x, tid = threadIdx.x;
  __shared__ float red[256];
  float acc = 0.f;
  for(int k = tid; k < CROSS_; k += 256){
    float s = 0.f;
    for(int t = 0; t < NTOK; ++t)
      s += enc[(size_t)(b*48 + t)*CROSS_ + k];       // dis tokens = enc[:, :16]
    acc += w_gate[k] * s;
  }
  red[tid] = acc; __syncthreads();
  for(int off = 128; off > 0; off >>= 1){
    if(tid < off) red[tid] += red[tid+off];
    __syncthreads();
  }
  if(tid == 0){
    float shift = red[0]*(1.f/16.f) + b_gate[0];
    gates[b*2+0] = 1.f/(1.f+__expf(shift - aLog[0]));     // sigmoid(aLog - shift)
    gates[b*2+1] = 1.f/(1.f+__expf(-(dLog[0] + shift)));  // sigmoid(dLog + shift)
  }
}

// --------------------------------------------------------------- kv gemm ---
// C[tau][b][t][n] = tokens(tau) @ W(tau)^T ; M=512 (b*16+t), N=1280, K=768
__global__ __launch_bounds__(256) void kv_gemm(const ushort_t* __restrict__ enc,
      const ushort_t* __restrict__ wk,  const ushort_t* __restrict__ wv,
      const ushort_t* __restrict__ wkd, const ushort_t* __restrict__ wvd,
      ushort_t* __restrict__ kv){
  __shared__ __align__(16) ushort_t As[128*64];
  __shared__ __align__(16) ushort_t Bs[128*64];
  const int tau = blockIdx.z;
  const ushort_t* W = (tau==0)? wk : (tau==1)? wv : (tau==2)? wkd : wvd;
  const int tok_off = (tau < 2) ? NTOK : 0;   // anat = enc[:,16:32], dis = enc[:,0:16]
  const int m0 = blockIdx.x*128, n0 = blockIdx.y*128;
  const int tid = threadIdx.x, l = tid & 63, w = tid >> 6;
  const int wm = (w&1)*64, wn = (w>>1)*64;
  const f32x4 fz = {0.f,0.f,0.f,0.f};
  f32x4 acc[4][4];
  #pragma unroll
  for(int i=0;i<4;++i){
    #pragma unroll
    for(int j=0;j<4;++j) acc[i][j] = fz;
  }
  for(int kt = 0; kt < CROSS_/64; ++kt){
    const int k0 = kt*64;
    #pragma unroll
    for(int i=0;i<4;++i){
      int row = (w*4+i)*8 + (l>>3);
      int c   = l & 7;
      int gm  = m0 + row;
      int er  = (gm>>4)*48 + tok_off + (gm&15);
      gload_lds16(enc + (size_t)er*CROSS_ + k0 + c*8, As + (w*4+i)*512);
      gload_lds16(W  + (size_t)(n0+row)*CROSS_ + k0 + c*8, Bs + (w*4+i)*512);
    }
    __syncthreads();
    #pragma unroll
    for(int ks = 0; ks < 64; ks += 32){
      bf16x8 a[4], bq[4];
      #pragma unroll
      for(int i=0;i<4;++i) a[i]  = *(const bf16x8*)&As[(wm+i*16+(l&15))*64 + ks + (l>>4)*8];
      #pragma unroll
      for(int j=0;j<4;++j) bq[j] = *(const bf16x8*)&Bs[(wn+j*16+(l&15))*64 + ks + (l>>4)*8];
      #pragma unroll
      for(int i=0;i<4;++i){
        #pragma unroll
        for(int j=0;j<4;++j)
          acc[i][j] = __builtin_amdgcn_mfma_f32_16x16x32_bf16(a[i], bq[j], acc[i][j], 0,0,0);
      }
    }
    __syncthreads();
  }
  #pragma unroll
  for(int i=0;i<4;++i){
    #pragma unroll
    for(int j=0;j<4;++j){
      #pragma unroll
      for(int r=0;r<4;++r){
        int m = m0 + wm + i*16 + (l>>4)*4 + r;
        int n = n0 + wn + j*16 + (l&15);
        int b = m >> 4, t = m & 15;
        kv[(((size_t)tau*B_ + b)*NTOK + t)*D_ + n] = f2b(acc[i][j][r]);
      }
    }
  }
}

// ------------------------------------------------- gemm1 + fused attention -
// q = X @ Wq^T for a 128x128 tile (= 128 s-rows x 2 heads), then attention
// against 16 anat + 16 dis keys, gated mix, z written bf16 to Z.
__global__ __launch_bounds__(256,3) void gemm1_attn(
      const ushort_t* __restrict__ X, const ushort_t* __restrict__ Wq,
      const ushort_t* __restrict__ kv, const float* __restrict__ gates,
      ushort_t* __restrict__ Z){
  __shared__ __align__(16) union {
    struct { ushort_t As[128*64]; ushort_t Bs[128*64]; } st;              // 32768 B
    struct { union { ushort_t qs[128*132];                                // 33792 B
                     ushort_t ps[4][64*44]; } u;                          // 22528 B
             ushort_t ks[2*2*16*72];                                      //  9216 B
             ushort_t vts[2*64*40]; } ep;                                 // 10240 B
  } sm;                                                                   // 53248 B -> 3 blk/CU
  int m0, n0; decode_tile(blockIdx.x, m0, n0);
  const int tid = threadIdx.x, l = tid & 63, w = tid >> 6;
  const int wm = (w&1)*64, wn = (w>>1)*64;
  const int b = m0 >> 10;                       // 1024 rows per batch
  const f32x4 fz = {0.f,0.f,0.f,0.f};
  f32x4 acc[4][4];
  #pragma unroll
  for(int i=0;i<4;++i){
    #pragma unroll
    for(int j=0;j<4;++j) acc[i][j] = fz;
  }
  for(int kt = 0; kt < D_/64; ++kt){
    const int k0 = kt*64;
    #pragma unroll
    for(int i=0;i<4;++i){
      int row = (w*4+i)*8 + (l>>3);
      int c   = l & 7;
      gload_lds16(X  + (size_t)(m0+row)*D_ + k0 + c*8, sm.st.As + (w*4+i)*512);
      gload_lds16(Wq + (size_t)(n0+row)*D_ + k0 + c*8, sm.st.Bs + (w*4+i)*512);
    }
    __syncthreads();
    #pragma unroll
    for(int ks = 0; ks < 64; ks += 32){
      bf16x8 a[4], bq[4];
      #pragma unroll
      for(int i=0;i<4;++i) a[i]  = *(const bf16x8*)&sm.st.As[(wm+i*16+(l&15))*64 + ks + (l>>4)*8];
      #pragma unroll
      for(int j=0;j<4;++j) bq[j] = *(const bf16x8*)&sm.st.Bs[(wn+j*16+(l&15))*64 + ks + (l>>4)*8];
      #pragma unroll
      for(int i=0;i<4;++i){
        #pragma unroll
        for(int j=0;j<4;++j)
          acc[i][j] = __builtin_amdgcn_mfma_f32_16x16x32_bf16(a[i], bq[j], acc[i][j], 0,0,0);
      }
    }
    __syncthreads();
  }
  // --- epilogue: q tile -> LDS (bf16), stage K (row-major) and V^T ---------
  #pragma unroll
  for(int i=0;i<4;++i){
    #pragma unroll
    for(int j=0;j<4;++j){
      #pragma unroll
      for(int r=0;r<4;++r)
        sm.ep.u.qs[(wm+i*16+(l>>4)*4+r)*132 + wn + j*16 + (l&15)] = f2b(acc[i][j][r]);
    }
  }
  // K: ks[h][tk][t][d]  (tk: 0=k_anat(tensor0), 1=k_dis(tensor2))
  for(int id = tid; id < 512; id += 256){
    int h  = id >> 8, rem = id & 255;
    int tk = rem >> 7, t = (rem>>3)&15, c = rem&7;
    int tensor = tk*2;
    const ushort_t* src = kv + (((size_t)tensor*B_ + b)*NTOK + t)*D_ + n0 + h*64 + c*8;
    *(uint4*)&sm.ep.ks[((h*2+tk)*16 + t)*72 + c*8] = *(const uint4*)src;
  }
  // V^T: vts[h][d][t'] with t' = t + 16*(dis)  (tensor 1 = v_anat, 3 = v_dis)
  for(int id = tid; id < 512; id += 256){
    int h = id >> 8, rem = id & 255;
    int tp = rem >> 3, c = rem & 7;
    int tensor = (tp < 16) ? 1 : 3;
    int t = tp & 15;
    const ushort_t* src = kv + (((size_t)tensor*B_ + b)*NTOK + t)*D_ + n0 + h*64 + c*8;
    uint4 v = *(const uint4*)src;
    const ushort_t* pv = (const ushort_t*)&v;
    #pragma unroll
    for(int e=0;e<8;++e) sm.ep.vts[(h*64 + c*8 + e)*40 + tp] = pv[e];
  }
  __syncthreads();
  // --- scores: QK^T via MFMA (wave = one head h, 64 s-rows) ---------------
  const int h = w >> 1, ws0 = (w&1)*64;
  const float gA = gates[b*2+0], gD = gates[b*2+1];
  f32x4 scA[4], scD[4];
  #pragma unroll
  for(int i=0;i<4;++i){ scA[i] = fz; scD[i] = fz; }
  #pragma unroll
  for(int ks0 = 0; ks0 < 64; ks0 += 32){
    bf16x8 qf[4];
    #pragma unroll
    for(int i=0;i<4;++i)
      qf[i] = *(const bf16x8*)&sm.ep.u.qs[(ws0+i*16+(l&15))*132 + h*64 + ks0 + (l>>4)*8];
    bf16x8 kA = *(const bf16x8*)&sm.ep.ks[((h*2+0)*16 + (l&15))*72 + ks0 + (l>>4)*8];
    bf16x8 kD = *(const bf16x8*)&sm.ep.ks[((h*2+1)*16 + (l&15))*72 + ks0 + (l>>4)*8];
    #pragma unroll
    for(int i=0;i<4;++i){
      scA[i] = __builtin_amdgcn_mfma_f32_16x16x32_bf16(qf[i], kA, scA[i], 0,0,0);
      scD[i] = __builtin_amdgcn_mfma_f32_16x16x32_bf16(qf[i], kD, scD[i], 0,0,0);
    }
  }
  __syncthreads();   // qs region dead; reuse for per-wave ps
  // --- softmax over 16 keys (t = lane&15), separate per tensor, gated -----
  #pragma unroll
  for(int i=0;i<4;++i){
    #pragma unroll
    for(int r=0;r<4;++r){
      float vA = scA[i][r]*SCALE_, vD = scD[i][r]*SCALE_;
      float mA = vA, mD = vD;
      #pragma unroll
      for(int off=1; off<16; off<<=1){
        mA = fmaxf(mA, __shfl_xor(mA, off));
        mD = fmaxf(mD, __shfl_xor(mD, off));
      }
      float eA = __expf(vA - mA), eD = __expf(vD - mD);
      float sA = eA, sD = eD;
      #pragma unroll
      for(int off=1; off<16; off<<=1){
        sA += __shfl_xor(sA, off);
        sD += __shfl_xor(sD, off);
      }
      int lr = i*16 + (l>>4)*4 + r;           // local row within wave's strip
      sm.ep.u.ps[w][lr*44 + 0  + (l&15)] = f2b(gA*eA/sA);
      sm.ep.u.ps[w][lr*44 + 16 + (l&15)] = f2b(gD*eD/sD);
    }
  }
  // --- PV: [gA*P_A | gD*P_D] (64x32) @ [V_A;V_D] (32x64), K=32 one MFMA ---
  f32x4 z[4][4];
  #pragma unroll
  for(int i=0;i<4;++i){
    #pragma unroll
    for(int j=0;j<4;++j) z[i][j] = fz;
  }
  bf16x8 pa[4], vb[4];
  #pragma unroll
  for(int i=0;i<4;++i) pa[i] = *(const bf16x8*)&sm.ep.u.ps[w][(i*16+(l&15))*44 + (l>>4)*8];
  #pragma unroll
  for(int j=0;j<4;++j) vb[j] = *(const bf16x8*)&sm.ep.vts[(h*64 + j*16 + (l&15))*40 + (l>>4)*8];
  #pragma unroll
  for(int i=0;i<4;++i){
    #pragma unroll
    for(int j=0;j<4;++j)
      z[i][j] = __builtin_amdgcn_mfma_f32_16x16x32_bf16(pa[i], vb[j], z[i][j], 0,0,0);
  }
  #pragma unroll
  for(int i=0;i<4;++i){
    #pragma unroll
    for(int j=0;j<4;++j){
      #pragma unroll
      for(int r=0;r<4;++r){
        int row = m0 + ws0 + i*16 + (l>>4)*4 + r;
        int col = n0 + h*64 + j*16 + (l&15);
        Z[(size_t)row*D_ + col] = f2b(z[i][j][r]);
      }
    }
  }
}

// ----------------------------------------------- gemm2: out-proj + resid ---
__global__ __launch_bounds__(256) void gemm2(
      const ushort_t* __restrict__ Zin, const ushort_t* __restrict__ Wo,
      const float* __restrict__ bias, const float* __restrict__ resid,
      float* __restrict__ out){
  __shared__ __align__(16) ushort_t As[128*64];
  __shared__ __align__(16) ushort_t Bs[128*64];
  int m0, n0; decode_tile(blockIdx.x, m0, n0);
  const int tid = threadIdx.x, l = tid & 63, w = tid >> 6;
  const int wm = (w&1)*64, wn = (w>>1)*64;
  const f32x4 fz = {0.f,0.f,0.f,0.f};
  f32x4 acc[4][4];
  #pragma unroll
  for(int i=0;i<4;++i){
    #pragma unroll
    for(int j=0;j<4;++j) acc[i][j] = fz;
  }
  for(int kt = 0; kt < D_/64; ++kt){
    const int k0 = kt*64;
    #pragma unroll
    for(int i=0;i<4;++i){
      int row = (w*4+i)*8 + (l>>3);
      int c   = l & 7;
      gload_lds16(Zin + (size_t)(m0+row)*D_ + k0 + c*8, As + (w*4+i)*512);
      gload_lds16(Wo  + (size_t)(n0+row)*D_ + k0 + c*8, Bs + (w*4+i)*512);
    }
    __syncthreads();
    #pragma unroll
    for(int ks = 0; ks < 64; ks += 32){
      bf16x8 a[4], bq[4];
      #pragma unroll
      for(int i=0;i<4;++i) a[i]  = *(const bf16x8*)&As[(wm+i*16+(l&15))*64 + ks + (l>>4)*8];
      #pragma unroll
      for(int j=0;j<4;++j) bq[j] = *(const bf16x8*)&Bs[(wn+j*16+(l&15))*64 + ks + (l>>4)*8];
      #pragma unroll
      for(int i=0;i<4;++i){
        #pragma unroll
        for(int j=0;j<4;++j)
          acc[i][j] = __builtin_amdgcn_mfma_f32_16x16x32_bf16(a[i], bq[j], acc[i][j], 0,0,0);
      }
    }
    __syncthreads();
  }
  float bj[4];
  #pragma unroll
  for(int j=0;j<4;++j) bj[j] = bias[n0 + wn + j*16 + (l&15)];
  #pragma unroll
  for(int i=0;i<4;++i){
    #pragma unroll
    for(int j=0;j<4;++j){
      #pragma unroll
      for(int r=0;r<4;++r){
        int m = m0 + wm + i*16 + (l>>4)*4 + r;
        int n = n0 + wn + j*16 + (l&15);
        out[(size_t)m*D_ + n] = acc[i][j][r] + bj[j] + resid[(size_t)m*D_ + n];
      }
    }
  }
}

// --------------------------------------------------------------------------
extern "C" void kernel_launch(void* const* d_in, const int* in_sizes, int n_in,
                              void* d_out, int out_size, void* d_ws, size_t ws_size,
                              hipStream_t stream){
  const float* hidden = (const float*)d_in[0];
  const float* enc    = (const float*)d_in[1];
  const float* w_q    = (const float*)d_in[2];
  const float* w_k    = (const float*)d_in[3];
  const float* w_v    = (const float*)d_in[4];
  const float* w_kd   = (const float*)d_in[5];
  const float* w_vd   = (const float*)d_in[6];
  const float* w_gate = (const float*)d_in[7];
  const float* b_gate = (const float*)d_in[8];
  const float* aLog   = (const float*)d_in[9];
  const float* dLog   = (const float*)d_in[10];
  const float* w_out  = (const float*)d_in[11];
  const float* b_out  = (const float*)d_in[12];
  float* out = (float*)d_out;

  char* ws = (char*)d_ws;
  ushort_t* z_bf   = (ushort_t*)(ws + 0);           // 83,886,080 B
  ushort_t* kv_bf  = (ushort_t*)(ws + 83886080);    //  5,242,880 B
  ushort_t* wq_bf  = (ushort_t*)(ws + 89128960);    //  3,276,800 B
  ushort_t* wk_bf  = (ushort_t*)(ws + 92405760);    //  1,966,080 B
  ushort_t* wv_bf  = (ushort_t*)(ws + 94371840);    //  1,966,080 B
  ushort_t* wkd_bf = (ushort_t*)(ws + 96337920);    //  1,966,080 B
  ushort_t* wvd_bf = (ushort_t*)(ws + 98304000);    //  1,966,080 B
  ushort_t* wo_bf  = (ushort_t*)(ws + 100270080);   //  3,276,800 B
  ushort_t* enc_bf = (ushort_t*)(ws + 103546880);   //  2,359,296 B
  float*    gates  = (float*)   (ws + 105906176);   //        256 B

  // hidden bf16 lives in the FIRST HALF OF d_out (168 MB f32 buffer; gemm1
  // consumes it fully before gemm2 writes d_out — stream-ordered, safe).
  ushort_t* hid_bf = (ushort_t*)d_out;              // 83,886,080 B <= out bytes

  CvtArgs ca;
  ca.src[0]=w_q;   ca.dst[0]=wq_bf;  ca.n[0]=D_*D_;
  ca.src[1]=w_k;   ca.dst[1]=wk_bf;  ca.n[1]=D_*CROSS_;
  ca.src[2]=w_v;   ca.dst[2]=wv_bf;  ca.n[2]=D_*CROSS_;
  ca.src[3]=w_kd;  ca.dst[3]=wkd_bf; ca.n[3]=D_*CROSS_;
  ca.src[4]=w_vd;  ca.dst[4]=wvd_bf; ca.n[4]=D_*CROSS_;
  ca.src[5]=w_out; ca.dst[5]=wo_bf;  ca.n[5]=D_*D_;
  ca.src[6]=enc;   ca.dst[6]=enc_bf; ca.n[6]=B_*48*CROSS_;
  cvt_kernel<<<dim3(1600,7), 256, 0, stream>>>(ca);
  cvt_big<<<20480, 256, 0, stream>>>(hidden, hid_bf, B_*S_*D_);

  gates_kernel<<<32, 256, 0, stream>>>(enc, w_gate, b_gate, aLog, dLog, gates);
  kv_gemm<<<dim3(4,10,4), 256, 0, stream>>>(enc_bf, wk_bf, wv_bf, wkd_bf, wvd_bf, kv_bf);
  gemm1_attn<<<2560, 256, 0, stream>>>(hid_bf, wq_bf, kv_bf, gates, z_bf);
  gemm2<<<2560, 256, 0, stream>>>(z_bf, wo_bf, b_out, hidden, out);
}